// Round 14
// baseline (343.410 us; speedup 1.0000x reference)
//
#include <hip/hip_runtime.h>
#include <hip/hip_bf16.h>

#define B_ 2
#define L_ 1024
#define H_ 768
#define A_ 12
#define E_ 24
#define M_ 8
#define P_ 552
#define EMB_ 768
#define BLK_ 64
#define NBLK_ 12
#define NL_ 97
#define NP_ (B_*P_)   // 1104
#define KTOT_ 49152   // EMB_*BLK_
#define TP_ 8
#define NC_ 8         // rs split-K planes

typedef float f32x4 __attribute__((ext_vector_type(4)));
typedef _Float16 f16x8 __attribute__((ext_vector_type(8)));

static __device__ __forceinline__ unsigned short f2h(float f){
    _Float16 h = (_Float16)f;
    unsigned short u; __builtin_memcpy(&u, &h, 2); return u;
}

// Tiled transposed layout: [col/8][k/8][col%8][k%8]  (f16 elements).
// Same size as [col][k], but a column's 8-k chunk is 16B inside a 128B tile
// shared by 8 columns -> writes/reads become KB-scale contiguous bursts and
// the pow2 column stride (channel camping) disappears.
static __device__ __forceinline__ size_t bt_idx(int col, int k, int Ktot){
    return ((size_t)(col >> 3) * (Ktot >> 3) + (k >> 3)) * 64 + ((col & 7) << 3) + (k & 7);
}

// async global->LDS, 16B per lane; lds base is wave-uniform, global addr per-lane.
static __device__ __forceinline__ void gload_lds16(const unsigned short* g, unsigned short* l){
    __builtin_amdgcn_global_load_lds(
        (const __attribute__((address_space(1))) unsigned int*)(const void*)g,
        (__attribute__((address_space(3))) unsigned int*)(void*)l, 16, 0, 0);
}

// ---------------- ent_emb: masked logsumexp over mentions ----------------
__global__ void k_ent_emb(const float* __restrict__ seq, const float* __restrict__ mask,
                          const int* __restrict__ midx, float* __restrict__ ent_emb)
{
    int be = blockIdx.x;
    int b = be / E_;
    int h = threadIdx.x;
    float v[M_];
    float mx = -1e30f;
    #pragma unroll
    for (int m = 0; m < M_; ++m) {
        float w = mask[be*M_ + m];
        int p = midx[be*M_ + m] + 1;
        float x = (w > 0.f) ? seq[(b*L_ + p)*H_ + h] : -1e30f;
        v[m] = x; mx = fmaxf(mx, x);
    }
    float s = 0.f;
    #pragma unroll
    for (int m = 0; m < M_; ++m) s += expf(v[m] - mx);
    ent_emb[be*H_ + h] = mx + logf(s);
}

// ---------------- ent_att: mention-averaged attention rows ----------------
__global__ void k_ent_att(const float* __restrict__ att, const float* __restrict__ mask,
                          const int* __restrict__ midx, float* __restrict__ ent_att)
{
    int bea = blockIdx.x;
    int a = bea % A_;
    int be = bea / A_;
    int b = be / E_;
    float cnt = 0.f;
    #pragma unroll
    for (int m = 0; m < M_; ++m) cnt += mask[be*M_ + m];
    cnt = fmaxf(cnt, 1.f);
    float inv = 1.f / cnt;
    for (int l = threadIdx.x; l < L_; l += blockDim.x) {
        float acc = 0.f;
        #pragma unroll
        for (int m = 0; m < M_; ++m) {
            float w = mask[be*M_ + m];
            if (w > 0.f) {
                int p = midx[be*M_ + m] + 1;
                acc += w * att[((size_t)(b*A_ + a)*L_ + p)*L_ + l];
            }
        }
        ent_att[(size_t)(be*A_ + a)*L_ + l] = acc * inv;
    }
}

// ---------------- ht_att: product over heads, mean, normalize ----------------
__global__ void k_ht_att(const float* __restrict__ ent_att, const int* __restrict__ hts,
                         float* __restrict__ ht_att)
{
    int bp = blockIdx.x;
    int b = bp / P_;
    int he = hts[bp*2 + 0];
    int te = hts[bp*2 + 1];
    const float* ha = ent_att + (size_t)(b*E_ + he)*A_*L_;
    const float* ta = ent_att + (size_t)(b*E_ + te)*A_*L_;
    __shared__ float red[256];
    float lsum = 0.f;
    for (int l = threadIdx.x; l < L_; l += 256) {
        float q = 0.f;
        #pragma unroll
        for (int a = 0; a < A_; ++a) q += ha[a*L_ + l] * ta[a*L_ + l];
        q *= (1.f / A_);
        ht_att[(size_t)bp*L_ + l] = q;
        lsum += q;
    }
    red[threadIdx.x] = lsum;
    __syncthreads();
    for (int s = 128; s > 0; s >>= 1) {
        if (threadIdx.x < s) red[threadIdx.x] += red[threadIdx.x + s];
        __syncthreads();
    }
    float scale = 1.f / (red[0] + 1e-30f);
    for (int l = threadIdx.x; l < L_; l += 256)
        ht_att[(size_t)bp*L_ + l] *= scale;
}

// ---------------- fast transpose body: [K][N] f32 -> tiled f16 (bt_idx) ----------------
template<int S>
static __device__ __forceinline__ void wt_fast_body(float (*tl)[65],
                                                    const float* __restrict__ in,
                                                    unsigned short* __restrict__ out,
                                                    int K, int N, int kt, int ct, bool guard)
{
    int tid = threadIdx.x;
    int tx = tid & 63, ty = tid >> 6;
    int k0 = kt*(S*64), c0 = ct*64;
    int col = tid >> 2, kq = tid & 3;
    bool cok = !guard || (c0 + tx < N);
    #pragma unroll
    for (int s = 0; s < S; ++s) {
        int kb = k0 + s*64;
        #pragma unroll
        for (int q = 0; q < 16; ++q) {
            int r = ty*16 + q;
            tl[r][tx] = cok ? in[(size_t)(kb + r)*N + c0 + tx] : 0.f;
        }
        __syncthreads();
        unsigned short pk[16];
        #pragma unroll
        for (int j = 0; j < 16; ++j) pk[j] = f2h(tl[kq*16 + j][col]);
        *(f16x8*)(out + bt_idx(c0+col, kb + kq*16,     K)) = *(f16x8*)&pk[0];
        *(f16x8*)(out + bt_idx(c0+col, kb + kq*16 + 8, K)) = *(f16x8*)&pk[8];
        __syncthreads();
    }
}

// mega-transpose: W2(1152) | seq(96) | Wh(48) | Wt(48) | Wb(192) = 1536 blocks
__global__ void k_wt_multi(const float* __restrict__ W2, unsigned short* __restrict__ w2t,
                           const float* __restrict__ seq, unsigned short* __restrict__ seqT,
                           const float* __restrict__ Wh, unsigned short* __restrict__ whT,
                           const float* __restrict__ Wt, unsigned short* __restrict__ wtT,
                           const float* __restrict__ Wb, unsigned short* __restrict__ wbt)
{
    __shared__ float tl[64][65];
    int t = blockIdx.x;
    if (t < 1152) {             // W2: K=49152, S=8 -> 96 ktiles x 12 ctiles
        wt_fast_body<8>(tl, W2, w2t, KTOT_, 768, t % 96, t / 96, false);
    } else if (t < 1248) {      // seq: per-batch K=1024, S=4 -> 4 ktiles x 12 ctiles
        t -= 1152; int b = t / 48; t %= 48;
        wt_fast_body<4>(tl, seq + (size_t)b*L_*H_, seqT + (size_t)b*768*L_, L_, 768, t % 4, t / 4, false);
    } else if (t < 1296) {      // Wh: K=1536, S=6 -> 4 ktiles x 12 ctiles
        t -= 1248;
        wt_fast_body<6>(tl, Wh, whT, 1536, 768, t % 4, t / 4, false);
    } else if (t < 1344) {      // Wt
        t -= 1296;
        wt_fast_body<6>(tl, Wt, wtT, 1536, 768, t % 4, t / 4, false);
    } else {                    // Wb: K=49152, S=8 -> 96 ktiles x 2 ctiles (N=97 pad 128)
        t -= 1344;
        wt_fast_body<8>(tl, Wb, wbt, KTOT_, NL_, t % 96, t / 96, true);
    }
}

// layer-2 weights: K=2304, S=4, grid (9, 12, 2)
__global__ void k_wt2_fast(const float* __restrict__ in0, unsigned short* __restrict__ out0,
                           const float* __restrict__ in1, unsigned short* __restrict__ out1)
{
    __shared__ float tl[64][65];
    const float* in = blockIdx.z ? in1 : in0;
    unsigned short* out = blockIdx.z ? out1 : out0;
    wt_fast_body<4>(tl, in, out, 2304, 768, blockIdx.x, blockIdx.y, false);
}

// ---------------- rs = ht_att @ seq : f16 MFMA, split-K x8 ----------------
__launch_bounds__(256, 3)
__global__ void k_rs_mfma(const float* __restrict__ ht_att, const unsigned short* __restrict__ seqT,
                          float* __restrict__ Cpart)
{
    __shared__ _Float16 Ash[128][64];
    __shared__ _Float16 Bsh[128][64];
    int tid = threadIdx.x;
    int lane = tid & 63, wid = tid >> 6;
    int wr = (wid >> 1)*64, wc = (wid & 1)*64;
    int r16 = lane & 15, g = lane >> 4;
    int z = blockIdx.z;                  // b*8 + kc
    int b = z >> 3, kc = z & 7;
    int c0 = blockIdx.x*128;
    int row0 = blockIdx.y*128;
    const float* At = ht_att + (size_t)b*P_*L_;
    const unsigned short* Bt = seqT + (size_t)b*768*L_;
    int srccol = (lane >> 3);
    int srcch  = (lane & 7) ^ (srccol & 7);

    f32x4 acc[4][4];
    #pragma unroll
    for (int a = 0; a < 4; ++a)
        #pragma unroll
        for (int bq = 0; bq < 4; ++bq) acc[a][bq] = (f32x4){0.f,0.f,0.f,0.f};

    for (int s = 0; s < 2; ++s) {
        __syncthreads();
        #pragma unroll
        for (int q = 0; q < 4; ++q) {
            int idx = q*256 + tid;
            int row = idx >> 3, ch = idx & 7;
            int p = row0 + row; if (p >= P_) p = P_ - 1;
            const float* pp = &At[(size_t)p*L_ + kc*128 + s*64 + ch*8];
            f32x4 a0 = *(const f32x4*)pp;
            f32x4 a1 = *(const f32x4*)(pp + 4);
            f16x8 h;
            h[0]=(_Float16)a0[0]; h[1]=(_Float16)a0[1]; h[2]=(_Float16)a0[2]; h[3]=(_Float16)a0[3];
            h[4]=(_Float16)a1[0]; h[5]=(_Float16)a1[1]; h[6]=(_Float16)a1[2]; h[7]=(_Float16)a1[3];
            *(f16x8*)&Ash[row][(ch ^ (row & 7))*8] = h;
        }
        #pragma unroll
        for (int q = 0; q < 4; ++q) {
            int colb = (q*4 + wid)*8;
            int col = colb + srccol;
            gload_lds16(&Bt[bt_idx(c0+col, kc*128 + s*64 + srcch*8, L_)],
                        (unsigned short*)&Bsh[colb][0]);
        }
        __syncthreads();
        #pragma unroll
        for (int kk = 0; kk < 2; ++kk) {
            f16x8 bfr[4];
            #pragma unroll
            for (int ni = 0; ni < 4; ++ni)
                bfr[ni] = *(f16x8*)&Bsh[wc + ni*16 + r16][((kk*4 + g) ^ (r16 & 7))*8];
            #pragma unroll
            for (int mi = 0; mi < 4; ++mi) {
                f16x8 afr = *(f16x8*)&Ash[wr + mi*16 + r16][((kk*4 + g) ^ (r16 & 7))*8];
                #pragma unroll
                for (int ni = 0; ni < 4; ++ni)
                    acc[mi][ni] = __builtin_amdgcn_mfma_f32_16x16x32_f16(afr, bfr[ni], acc[mi][ni], 0, 0, 0);
            }
        }
    }

    #pragma unroll
    for (int mi = 0; mi < 4; ++mi)
      #pragma unroll
      for (int ni = 0; ni < 4; ++ni)
        #pragma unroll
        for (int r = 0; r < 4; ++r) {
            int p = row0 + wr + mi*16 + g*4 + r;
            if (p < P_)
                Cpart[((size_t)kc*NP_ + b*P_ + p)*768 + c0 + wc + ni*16 + r16] = acc[mi][ni][r];
        }
}

__global__ void k_rs_reduce(const float* __restrict__ rspart, float* __restrict__ rs)
{
    int idx = blockIdx.x*256 + threadIdx.x;
    if (idx >= NP_*768/4) return;
    f32x4 s = {0.f,0.f,0.f,0.f};
    #pragma unroll
    for (int z = 0; z < NC_; ++z) s += *(const f32x4*)&rspart[(size_t)z*NP_*768 + (size_t)idx*4];
    *(f32x4*)&rs[(size_t)idx*4] = s;
}

// ---------------- legacy rs + gather (fallback path only) ----------------
__global__ void k_rs(const float* __restrict__ seq, const float* __restrict__ ht_att,
                     float* __restrict__ rs)
{
    int blk = blockIdx.x;
    int b = blk / (P_/TP_);
    int p0 = (blk % (P_/TP_)) * TP_;
    const float* sq = seq + (size_t)b*L_*H_;
    float acc[TP_][3];
    #pragma unroll
    for (int t = 0; t < TP_; ++t)
        #pragma unroll
        for (int c = 0; c < 3; ++c) acc[t][c] = 0.f;
    for (int l = 0; l < L_; ++l) {
        float w[TP_];
        #pragma unroll
        for (int t = 0; t < TP_; ++t) w[t] = ht_att[(size_t)(b*P_ + p0 + t)*L_ + l];
        #pragma unroll
        for (int c = 0; c < 3; ++c) {
            float v = sq[(size_t)l*H_ + threadIdx.x + 256*c];
            #pragma unroll
            for (int t = 0; t < TP_; ++t) acc[t][c] += w[t]*v;
        }
    }
    #pragma unroll
    for (int t = 0; t < TP_; ++t)
        #pragma unroll
        for (int c = 0; c < 3; ++c)
            rs[(size_t)(b*P_ + p0 + t)*H_ + threadIdx.x + 256*c] = acc[t][c];
}

__global__ void k_gather(const float* __restrict__ ent_emb, const int* __restrict__ hts,
                         float* __restrict__ hs, float* __restrict__ ts)
{
    int bp = blockIdx.x;
    int b = bp / P_;
    int he = hts[bp*2 + 0];
    int te = hts[bp*2 + 1];
    int h = threadIdx.x;
    hs[(size_t)bp*H_ + h] = ent_emb[(b*E_ + he)*H_ + h];
    ts[(size_t)bp*H_ + h] = ent_emb[(b*E_ + te)*H_ + h];
}

// ---------------- dual reduce + tanh ----------------
__global__ void k_gemm_reduce_tanh2(const float* __restrict__ gpA, const float* __restrict__ gpB,
                                    const float* __restrict__ biasA, const float* __restrict__ biasB,
                                    float* __restrict__ CA, float* __restrict__ CB, int nz)
{
    const float* Cpart = blockIdx.y ? gpB : gpA;
    const float* bias  = blockIdx.y ? biasB : biasA;
    float* C           = blockIdx.y ? CB : CA;
    int idx = blockIdx.x*256 + threadIdx.x;
    if (idx >= NP_*768/4) return;
    int c4 = (idx*4) % 768;
    f32x4 s = *(const f32x4*)&bias[c4];
    for (int z = 0; z < nz; ++z) s += *(const f32x4*)&Cpart[(size_t)z*NP_*768 + (size_t)idx*4];
    f32x4 r;
    #pragma unroll
    for (int j = 0; j < 4; ++j) r[j] = tanhf(s[j]);
    *(f32x4*)&C[(size_t)idx*4] = r;
}

// ---------------- legacy concat GEMM (fallback path only) ----------------
template<int NPARTS, bool DOTANH>
__global__ void k_gemm_concat(const float* __restrict__ A0, const float* __restrict__ A1,
                              const float* __restrict__ A2, const float* __restrict__ W,
                              const float* __restrict__ bias, float* __restrict__ C,
                              int Mrows)
{
    const int BK = 16;
    __shared__ float As[BK][64];
    __shared__ float Bs[BK][64];
    int tid = threadIdx.x;
    int ty = tid >> 4, tx = tid & 15;
    int by = blockIdx.y, bx = blockIdx.x;
    float acc[4][4] = {};
    const int K = NPARTS * 768;
    for (int kk0 = 0; kk0 < K; kk0 += BK) {
        const float* Ap = (kk0 < 768) ? A0 : ((NPARTS >= 3 && kk0 >= 1536) ? A2 : A1);
        int klocal = kk0 % 768;
        {
            int idx = tid * 4;
            int r = idx >> 4;
            int k = idx & 15;
            int row = by*64 + r;
            float4 v = make_float4(0.f,0.f,0.f,0.f);
            if (row < Mrows) v = *(const float4*)(Ap + (size_t)row*768 + klocal + k);
            As[k+0][r] = v.x; As[k+1][r] = v.y; As[k+2][r] = v.z; As[k+3][r] = v.w;
        }
        {
            int idx = tid * 4;
            int k = idx >> 6;
            int c = idx & 63;
            *(float4*)&Bs[k][c] = *(const float4*)(W + (size_t)(kk0 + k)*768 + bx*64 + c);
        }
        __syncthreads();
        #pragma unroll
        for (int k = 0; k < BK; ++k) {
            float a4[4], b4[4];
            *(float4*)a4 = *(float4*)&As[k][ty*4];
            *(float4*)b4 = *(float4*)&Bs[k][tx*4];
            #pragma unroll
            for (int i = 0; i < 4; ++i)
                #pragma unroll
                for (int j = 0; j < 4; ++j) acc[i][j] += a4[i]*b4[j];
        }
        __syncthreads();
    }
    #pragma unroll
    for (int i = 0; i < 4; ++i) {
        int row = by*64 + ty*4 + i;
        if (row >= Mrows) continue;
        #pragma unroll
        for (int j = 0; j < 4; ++j) {
            int col = bx*64 + tx*4 + j;
            float v = acc[i][j] + bias[col];
            if (DOTANH) v = tanhf(v);
            C[(size_t)row*768 + col] = v;
        }
    }
}

// ---------------- dual f16 MFMA concat GEMM (two GEMMs in one launch) ----------------
template<int NSTEP, bool GATHER0>
__launch_bounds__(256, 3)
__global__ void k_gemm_mfma2(const float* __restrict__ A0a, const float* __restrict__ A0b,
                             const float* __restrict__ A1, const float* __restrict__ A2,
                             const int* __restrict__ hts,
                             const unsigned short* __restrict__ WTa, const unsigned short* __restrict__ WTb,
                             float* __restrict__ Cpa, float* __restrict__ Cpb,
                             int Mrows, int Ktot, int partdiv, int nzhalf)
{
    __shared__ _Float16 Ash[128][64];
    __shared__ _Float16 Bsh[128][64];
    int tid = threadIdx.x;
    int lane = tid & 63, wid = tid >> 6;
    int wr = (wid >> 1)*64, wc = (wid & 1)*64;
    int r16 = lane & 15, g = lane >> 4;
    int zz = blockIdx.z;
    int half = zz / nzhalf;
    int z = zz % nzhalf;
    const unsigned short* WT = half ? WTb : WTa;
    float* Cpart = half ? Cpb : Cpa;
    int part = z / partdiv, chunk = z % partdiv;
    int ka = chunk * (NSTEP*64);
    int kb = part*768 + ka;
    const float* A = (part == 0) ? (half ? A0b : A0a) : ((part == 1) ? A1 : A2);
    int c0 = blockIdx.x*128;
    int row0 = blockIdx.y*128;
    int srccol = (lane >> 3);
    int srcch  = (lane & 7) ^ (srccol & 7);

    f32x4 acc[4][4];
    #pragma unroll
    for (int a = 0; a < 4; ++a)
        #pragma unroll
        for (int b = 0; b < 4; ++b) acc[a][b] = (f32x4){0.f,0.f,0.f,0.f};

    for (int s = 0; s < NSTEP; ++s) {
        __syncthreads();
        #pragma unroll
        for (int q = 0; q < 4; ++q) {
            int idx = q*256 + tid;
            int row = idx >> 3, ch = idx & 7;
            int grow = row0 + row; if (grow >= Mrows) grow = Mrows - 1;
            const float* p;
            if (GATHER0 && part == 0) {
                int bb_ = grow / P_;
                int e = hts[grow*2 + half];
                p = &A0a[((size_t)(bb_*E_ + e))*768 + ka + s*64 + ch*8];
            } else {
                p = &A[(size_t)grow*768 + ka + s*64 + ch*8];
            }
            f32x4 a0 = *(const f32x4*)p;
            f32x4 a1 = *(const f32x4*)(p + 4);
            f16x8 h;
            h[0]=(_Float16)a0[0]; h[1]=(_Float16)a0[1]; h[2]=(_Float16)a0[2]; h[3]=(_Float16)a0[3];
            h[4]=(_Float16)a1[0]; h[5]=(_Float16)a1[1]; h[6]=(_Float16)a1[2]; h[7]=(_Float16)a1[3];
            *(f16x8*)&Ash[row][(ch ^ (row & 7))*8] = h;
        }
        #pragma unroll
        for (int q = 0; q < 4; ++q) {
            int colb = (q*4 + wid)*8;
            int col = colb + srccol;
            gload_lds16(&WT[bt_idx(c0+col, kb + s*64 + srcch*8, Ktot)],
                        (unsigned short*)&Bsh[colb][0]);
        }
        __syncthreads();
        #pragma unroll
        for (int kk = 0; kk < 2; ++kk) {
            f16x8 bfr[4];
            #pragma unroll
            for (int ni = 0; ni < 4; ++ni)
                bfr[ni] = *(f16x8*)&Bsh[wc + ni*16 + r16][((kk*4 + g) ^ (r16 & 7))*8];
            #pragma unroll
            for (int mi = 0; mi < 4; ++mi) {
                f16x8 afr = *(f16x8*)&Ash[wr + mi*16 + r16][((kk*4 + g) ^ (r16 & 7))*8];
                #pragma unroll
                for (int ni = 0; ni < 4; ++ni)
                    acc[mi][ni] = __builtin_amdgcn_mfma_f32_16x16x32_f16(afr, bfr[ni], acc[mi][ni], 0, 0, 0);
            }
        }
    }

    #pragma unroll
    for (int mi = 0; mi < 4; ++mi)
      #pragma unroll
      for (int ni = 0; ni < 4; ++ni)
        #pragma unroll
        for (int r = 0; r < 4; ++r) {
            int row = row0 + wr + mi*16 + g*4 + r;
            if (row < Mrows)
                Cpart[((size_t)z*Mrows + row)*768 + c0 + wc + ni*16 + r16] = acc[mi][ni][r];
        }
}

// ---------------- f16 MFMA block-bilinear GEMM (R9 proven structure) ----------------
template<int ILEN, bool SWZ>
__launch_bounds__(256, 3)
__global__ void k_bb_mfma(const float* __restrict__ U, const float* __restrict__ V,
                          const unsigned short* __restrict__ BT, float* __restrict__ Cpart,
                          int Mrows, int ldc)
{
    const int ISPLIT = 64 / ILEN;
    __shared__ unsigned short Ush[128][ILEN + 2];
    __shared__ _Float16 Bs[2][128][64];
    int tid = threadIdx.x;
    int lane = tid & 63, wid = tid >> 6;
    int wr = (wid >> 1)*64, wc = (wid & 1)*64;
    int r16 = lane & 15, g = lane >> 4;
    int bx = blockIdx.x, by = blockIdx.y, z = blockIdx.z;
    if (SWZ) {
        int h = bx + 6*by + 54*z;
        int x = h & 7, j = h >> 3;
        int p = x*9 + j/9;
        by = j % 9;
        bx = p % 6;
        z  = p / 6;
    }
    int kz = z / ISPLIT, si = z % ISPLIT;
    int ibeg = si * ILEN;
    int c0 = bx*128;
    int row0 = by*128;
    int srccol = (lane >> 3);
    int srcch  = (lane & 7) ^ (srccol & 7);

    #pragma unroll
    for (int q = 0; q < (128*ILEN)/1024; ++q) {
        int idx = (q*256 + tid)*4;
        int r = idx / ILEN, c = idx % ILEN;
        int row = row0 + r; if (row >= Mrows) row = Mrows - 1;
        f32x4 v = *(const f32x4*)&U[(size_t)row*EMB_ + kz*64 + ibeg + c];
        Ush[r][c+0] = f2h(v[0]); Ush[r][c+1] = f2h(v[1]);
        Ush[r][c+2] = f2h(v[2]); Ush[r][c+3] = f2h(v[3]);
    }
    f16x8 vfh[2][4];
    #pragma unroll
    for (int kk = 0; kk < 2; ++kk)
      #pragma unroll
      for (int mi = 0; mi < 4; ++mi) {
        int row = row0 + wr + mi*16 + r16; if (row >= Mrows) row = Mrows - 1;
        const float* p = &V[(size_t)row*EMB_ + kz*64 + kk*32 + g*8];
        f16x8 t;
        #pragma unroll
        for (int e = 0; e < 8; ++e) t[e] = (_Float16)p[e];
        vfh[kk][mi] = t;
      }
    // stage panel i=ibeg into Bs[0] via async global->LDS
    #pragma unroll
    for (int q = 0; q < 4; ++q) {
        int colb = (q*4 + wid)*8;
        int col = colb + srccol;
        gload_lds16(&BT[bt_idx(c0+col, kz*4096 + ibeg*64 + srcch*8, KTOT_)],
                    (unsigned short*)&Bs[0][colb][0]);
    }
    __syncthreads();

    f32x4 acc[4][4];
    #pragma unroll
    for (int a = 0; a < 4; ++a)
        #pragma unroll
        for (int b = 0; b < 4; ++b) acc[a][b] = (f32x4){0.f,0.f,0.f,0.f};

    for (int ii = 0; ii < ILEN; ++ii) {
        int cur = ii & 1, nxt = cur ^ 1;
        if (ii < ILEN-1) {
            #pragma unroll
            for (int q = 0; q < 4; ++q) {
                int colb = (q*4 + wid)*8;
                int col = colb + srccol;
                gload_lds16(&BT[bt_idx(c0+col, kz*4096 + (ibeg+ii+1)*64 + srcch*8, KTOT_)],
                            (unsigned short*)&Bs[nxt][colb][0]);
            }
        }
        f16x8 u8[4];
        #pragma unroll
        for (int mi = 0; mi < 4; ++mi) {
            unsigned short ub = Ush[wr + mi*16 + r16][ii];
            _Float16 uh; __builtin_memcpy(&uh, &ub, 2);
            #pragma unroll
            for (int e = 0; e < 8; ++e) u8[mi][e] = uh;
        }
        #pragma unroll
        for (int kk = 0; kk < 2; ++kk) {
            f16x8 bfr[4];
            #pragma unroll
            for (int ni = 0; ni < 4; ++ni) {
                int row = wc + ni*16 + r16;
                bfr[ni] = *(f16x8*)&Bs[cur][row][((kk*4 + g) ^ (r16 & 7))*8];
            }
            #pragma unroll
            for (int mi = 0; mi < 4; ++mi) {
                f16x8 afr = u8[mi] * vfh[kk][mi];
                #pragma unroll
                for (int ni = 0; ni < 4; ++ni)
                    acc[mi][ni] = __builtin_amdgcn_mfma_f32_16x16x32_f16(afr, bfr[ni], acc[mi][ni], 0, 0, 0);
            }
        }
        __syncthreads();
    }

    #pragma unroll
    for (int mi = 0; mi < 4; ++mi)
      #pragma unroll
      for (int ni = 0; ni < 4; ++ni)
        #pragma unroll
        for (int r = 0; r < 4; ++r) {
            int row = row0 + wr + mi*16 + g*4 + r;
            if (row < Mrows)
                Cpart[((size_t)z*Mrows + row)*ldc + c0 + wc + ni*16 + r16] = acc[mi][ni][r];
        }
}

// ---------------- reduce split-K partials (+bias) ----------------
__global__ void k_reduce_feat(const float* __restrict__ part, const float* __restrict__ bias,
                              float* __restrict__ out)
{
    int idx = blockIdx.x*256 + threadIdx.x;
    if (idx >= (NP_*768)/4) return;
    int c4 = (idx*4) % 768;
    f32x4 s = *(const f32x4*)&bias[c4];
    #pragma unroll
    for (int z = 0; z < NBLK_; ++z) s += *(const f32x4*)&part[(size_t)z*NP_*768 + (size_t)idx*4];
    *(f32x4*)&out[(size_t)idx*4] = s;
}

__global__ void k_reduce_logits(const float* __restrict__ part, const float* __restrict__ bb,
                                float* __restrict__ out, int nz)
{
    int idx = blockIdx.x*256 + threadIdx.x;
    if (idx >= NP_*NL_) return;
    int n = idx / NL_, c = idx % NL_;
    float s = bb[c];
    for (int z = 0; z < nz; ++z) s += part[(size_t)z*NP_*128 + (size_t)n*128 + c];
    out[idx] = s;
}

// ---------------- fallback fp32 bilinear GEMM ----------------
template<bool GUARD, bool SPLITK>
__global__ void k_bbgemm(const float* __restrict__ U, const float* __restrict__ V,
                         const float* __restrict__ W, const float* __restrict__ bias,
                         float* __restrict__ C, int Mrows, int Ncols, int ldw, int ldc)
{
    __shared__ float Us[64][68];
    __shared__ float Vs[64][68];
    __shared__ float Bsh[16][64];
    int tid = threadIdx.x;
    int ty = tid >> 4, tx = tid & 15;
    int by = blockIdx.y, bx = blockIdx.x;
    int c0 = bx*64;
    float acc[4][4] = {};
    int kbeg = SPLITK ? blockIdx.z : 0;
    int kend = SPLITK ? blockIdx.z + 1 : NBLK_;
    for (int k = kbeg; k < kend; ++k) {
        #pragma unroll
        for (int e = 0; e < 4; ++e) {
            int idx = (e*256 + tid)*4;
            int r = idx >> 6, c = idx & 63;
            int row = by*64 + r;
            float4 u = make_float4(0.f,0.f,0.f,0.f), vv = make_float4(0.f,0.f,0.f,0.f);
            if (row < Mrows) {
                u  = *(const float4*)(U + (size_t)row*EMB_ + k*BLK_ + c);
                vv = *(const float4*)(V + (size_t)row*EMB_ + k*BLK_ + c);
            }
            *(float4*)&Us[r][c] = u;
            *(float4*)&Vs[r][c] = vv;
        }
        __syncthreads();
        for (int t = 0; t < 256; ++t) {
            int i = t >> 2;
            int jb = (t & 3) * 16;
            {
                int idx = tid * 4;
                int kk = idx >> 6, c = idx & 63;
                size_t wrow = (size_t)(k*256 + t)*16 + kk;
                if (GUARD) {
                    #pragma unroll
                    for (int q = 0; q < 4; ++q) {
                        int col = c0 + c + q;
                        Bsh[kk][c+q] = (col < Ncols) ? W[wrow*ldw + col] : 0.f;
                    }
                } else {
                    *(float4*)&Bsh[kk][c] = *(const float4*)(W + wrow*ldw + c0 + c);
                }
            }
            __syncthreads();
            float u[4];
            #pragma unroll
            for (int r = 0; r < 4; ++r) u[r] = Us[ty*4+r][i];
            #pragma unroll
            for (int kk = 0; kk < 16; ++kk) {
                float b4[4];
                *(float4*)b4 = *(float4*)&Bsh[kk][tx*4];
                #pragma unroll
                for (int r = 0; r < 4; ++r) {
                    float a = u[r] * Vs[ty*4+r][jb+kk];
                    #pragma unroll
                    for (int j = 0; j < 4; ++j) acc[r][j] += a*b4[j];
                }
            }
            __syncthreads();
        }
    }
    #pragma unroll
    for (int r = 0; r < 4; ++r) {
        int row = by*64 + ty*4 + r;
        if (row >= Mrows) continue;
        #pragma unroll
        for (int j = 0; j < 4; ++j) {
            int col = c0 + tx*4 + j;
            if (GUARD && col >= Ncols) continue;
            float v = acc[r][j];
            if (!SPLITK) v += bias[col];
            size_t out_idx = SPLITK ? ((size_t)(blockIdx.z*Mrows + row)*ldc + col)
                                    : ((size_t)row*ldc + col);
            C[out_idx] = v;
        }
    }
}

__global__ void k_logits_reduce_old(const float* __restrict__ part, const float* __restrict__ bb,
                                    float* __restrict__ out)
{
    int idx = blockIdx.x*256 + threadIdx.x;
    if (idx >= NP_*NL_) return;
    int col = idx % NL_;
    float s = bb[col];
    #pragma unroll
    for (int z = 0; z < NBLK_; ++z) s += part[(size_t)z*NP_*NL_ + idx];
    out[idx] = s;
}

extern "C" void kernel_launch(void* const* d_in, const int* in_sizes, int n_in,
                              void* d_out, int out_size, void* d_ws, size_t ws_size,
                              hipStream_t stream)
{
    (void)in_sizes; (void)n_in; (void)out_size;
    const float* seq  = (const float*)d_in[0];
    const float* att  = (const float*)d_in[1];
    const float* mask = (const float*)d_in[2];
    const float* Wh   = (const float*)d_in[3];
    const float* bh   = (const float*)d_in[4];
    const float* Wt   = (const float*)d_in[5];
    const float* bt   = (const float*)d_in[6];
    const float* Wh2  = (const float*)d_in[7];
    const float* bh2  = (const float*)d_in[8];
    const float* Wt2  = (const float*)d_in[9];
    const float* bt2  = (const float*)d_in[10];
    const float* W2   = (const float*)d_in[11];
    const float* b2   = (const float*)d_in[12];
    const float* Wb   = (const float*)d_in[13];
    const float* bb   = (const float*)d_in[14];
    const int* midx   = (const int*)d_in[15];
    const int* hts    = (const int*)d_in[16];
    float* out = (float*)d_out;
    float* ws  = (float*)d_ws;

    float* ent_emb = ws;                        // 36864
    float* ent_att = ent_emb + 36864;           // 589824 (mfma: whT after ht_att)
    float* ht_att  = ent_att + 589824;          // 1130496 (mfma: wh2T after rs)
    float* rs      = ht_att + 1130496;          // 847872 each below
    float* hs      = rs   + 847872;             // mfma path: seqT (f16)
    float* ts      = hs   + 847872;             // mfma path: wtT (f16)
    float* hs1     = ts   + 847872;
    float* ts1     = hs1  + 847872;
    float* feat    = ts1  + 847872;
    float* hs2     = feat + 847872;
    float* ts2     = hs2  + 847872;
    float* featpart = ts2 + 847872;             // 10174464 floats (multi-use scratch)
    float* spare    = featpart + 10174464;      // 1695744 floats (mfma: wt2T)
    unsigned short* w2t = (unsigned short*)(spare + 1695744);             // 37748736 shorts
    unsigned short* Rrgn = (unsigned short*)(spare + 1695744 + 18874368); // 6291456 shorts
    const size_t need_bytes = (size_t)42430464 * 4;      // ~169.7 MB
    const bool use_mfma = (ws_size >= need_bytes);

    // mfma-path aliases (sequential lifetimes):
    unsigned short* whT  = (unsigned short*)ent_att;  // 1179648 sh (exact fit)
    unsigned short* wtT  = (unsigned short*)ts;       // 1179648 sh <= 1695744
    unsigned short* wh2T = (unsigned short*)ht_att;   // 1769472 sh <= 2260992 (after rs done)
    unsigned short* wt2T = (unsigned short*)spare;    // 1769472 sh <= 3391488
    unsigned short* wbt  = Rrgn;                      // 6291456 sh (exact fit, persistent)
    unsigned short* seqT = (unsigned short*)hs;

    float* rspart  = featpart;                  // 8*1104*768
    float* gpA     = featpart;                  // 6 planes = 5087232
    float* gpB     = featpart + 5087232;
    float* logpart = featpart;                  // 48*1104*128

    k_ent_emb<<<dim3(B_*E_), dim3(H_), 0, stream>>>(seq, mask, midx, ent_emb);
    k_ent_att<<<dim3(B_*E_*A_), dim3(256), 0, stream>>>(att, mask, midx, ent_att);
    k_ht_att<<<dim3(NP_), dim3(256), 0, stream>>>(ent_att, hts, ht_att);

    if (use_mfma) {
        // all transposes whose outputs are ready (ent_att dead after ht_att)
        k_wt_multi<<<dim3(1536), dim3(256), 0, stream>>>(W2, w2t, seq, seqT,
                                                         Wh, whT, Wt, wtT, Wb, wbt);

        k_rs_mfma<<<dim3(6, 5, 16), dim3(256), 0, stream>>>(ht_att, seqT, rspart);
        k_rs_reduce<<<dim3(828), dim3(256), 0, stream>>>(rspart, rs);

        k_gemm_mfma2<4, true><<<dim3(6, 9, 12), dim3(256), 0, stream>>>(
            ent_emb, ent_emb, rs, rs, hts, whT, wtT, gpA, gpB, NP_, 1536, 3, 6);
        k_gemm_reduce_tanh2<<<dim3(828, 2), dim3(256), 0, stream>>>(gpA, gpB, bh, bt, hs1, ts1, 6);

        k_bb_mfma<64, true><<<dim3(6, 9, NBLK_), dim3(256), 0, stream>>>(hs1, ts1, w2t, featpart, NP_, 768);
        k_reduce_feat<<<dim3((NP_*768/4 + 255)/256), dim3(256), 0, stream>>>(featpart, b2, feat);

        // layer-2 weight transposes (ht_att dead after rs_mfma)
        k_wt2_fast<<<dim3(9, 12, 2), dim3(256), 0, stream>>>(Wh2, wh2T, Wt2, wt2T);

        k_gemm_mfma2<6, false><<<dim3(6, 9, 12), dim3(256), 0, stream>>>(
            hs1, ts1, rs, feat, hts, wh2T, wt2T, gpA, gpB, NP_, 2304, 2, 6);
        k_gemm_reduce_tanh2<<<dim3(828, 2), dim3(256), 0, stream>>>(gpA, gpB, bh2, bt2, hs2, ts2, 6);

        k_bb_mfma<16, false><<<dim3(1, 9, NBLK_*4), dim3(256), 0, stream>>>(hs2, ts2, wbt, logpart, NP_, 128);
        k_reduce_logits<<<dim3((NP_*NL_ + 255)/256), dim3(256), 0, stream>>>(logpart, bb, out, NBLK_*4);
    } else {
        k_rs<<<dim3(B_*(P_/TP_)), dim3(256), 0, stream>>>(seq, ht_att, rs);
        k_gather<<<dim3(NP_), dim3(H_), 0, stream>>>(ent_emb, hts, hs, ts);
        dim3 gg(12, (NP_+63)/64);
        k_gemm_concat<2, true><<<gg, dim3(256), 0, stream>>>(hs, rs, nullptr, Wh, bh, hs1, NP_);
        k_gemm_concat<2, true><<<gg, dim3(256), 0, stream>>>(ts, rs, nullptr, Wt, bt, ts1, NP_);
        float* lpart = featpart;
        k_bbgemm<false, false><<<gg, dim3(256), 0, stream>>>(hs1, ts1, W2, b2, feat, NP_, 768, 768, 768);
        k_gemm_concat<3, true><<<gg, dim3(256), 0, stream>>>(hs1, rs, feat, Wh2, bh2, hs2, NP_);
        k_gemm_concat<3, true><<<gg, dim3(256), 0, stream>>>(ts1, rs, feat, Wt2, bt2, ts2, NP_);
        k_bbgemm<true, true><<<dim3(2, (NP_+63)/64, NBLK_), dim3(256), 0, stream>>>(
            hs2, ts2, Wb, nullptr, lpart, NP_, NL_, NL_, NL_);
        k_logits_reduce_old<<<dim3((NP_*NL_ + 255)/256), dim3(256), 0, stream>>>(lpart, bb, out);
    }
}

// Round 15
// 315.034 us; speedup vs baseline: 1.0901x; 1.0901x over previous
//
#include <hip/hip_runtime.h>
#include <hip/hip_bf16.h>

#define B_ 2
#define L_ 1024
#define H_ 768
#define A_ 12
#define E_ 24
#define M_ 8
#define P_ 552
#define EMB_ 768
#define BLK_ 64
#define NBLK_ 12
#define NL_ 97
#define NP_ (B_*P_)   // 1104
#define KTOT_ 49152   // EMB_*BLK_
#define TP_ 8
#define NC_ 8         // rs split-K planes

typedef float f32x4 __attribute__((ext_vector_type(4)));
typedef _Float16 f16x8 __attribute__((ext_vector_type(8)));

static __device__ __forceinline__ unsigned short f2h(float f){
    _Float16 h = (_Float16)f;
    unsigned short u; __builtin_memcpy(&u, &h, 2); return u;
}

// async global->LDS, 16B per lane; lds base is wave-uniform, global addr per-lane.
static __device__ __forceinline__ void gload_lds16(const unsigned short* g, unsigned short* l){
    __builtin_amdgcn_global_load_lds(
        (const __attribute__((address_space(1))) unsigned int*)(const void*)g,
        (__attribute__((address_space(3))) unsigned int*)(void*)l, 16, 0, 0);
}

// ---------------- ent_emb: masked logsumexp over mentions ----------------
__global__ void k_ent_emb(const float* __restrict__ seq, const float* __restrict__ mask,
                          const int* __restrict__ midx, float* __restrict__ ent_emb)
{
    int be = blockIdx.x;
    int b = be / E_;
    int h = threadIdx.x;
    float v[M_];
    float mx = -1e30f;
    #pragma unroll
    for (int m = 0; m < M_; ++m) {
        float w = mask[be*M_ + m];
        int p = midx[be*M_ + m] + 1;
        float x = (w > 0.f) ? seq[(b*L_ + p)*H_ + h] : -1e30f;
        v[m] = x; mx = fmaxf(mx, x);
    }
    float s = 0.f;
    #pragma unroll
    for (int m = 0; m < M_; ++m) s += expf(v[m] - mx);
    ent_emb[be*H_ + h] = mx + logf(s);
}

// ---------------- ent_att: mention-averaged attention rows ----------------
__global__ void k_ent_att(const float* __restrict__ att, const float* __restrict__ mask,
                          const int* __restrict__ midx, float* __restrict__ ent_att)
{
    int bea = blockIdx.x;
    int a = bea % A_;
    int be = bea / A_;
    int b = be / E_;
    float cnt = 0.f;
    #pragma unroll
    for (int m = 0; m < M_; ++m) cnt += mask[be*M_ + m];
    cnt = fmaxf(cnt, 1.f);
    float inv = 1.f / cnt;
    for (int l = threadIdx.x; l < L_; l += blockDim.x) {
        float acc = 0.f;
        #pragma unroll
        for (int m = 0; m < M_; ++m) {
            float w = mask[be*M_ + m];
            if (w > 0.f) {
                int p = midx[be*M_ + m] + 1;
                acc += w * att[((size_t)(b*A_ + a)*L_ + p)*L_ + l];
            }
        }
        ent_att[(size_t)(be*A_ + a)*L_ + l] = acc * inv;
    }
}

// ---------------- ht_att: product over heads, mean, normalize ----------------
__global__ void k_ht_att(const float* __restrict__ ent_att, const int* __restrict__ hts,
                         float* __restrict__ ht_att)
{
    int bp = blockIdx.x;
    int b = bp / P_;
    int he = hts[bp*2 + 0];
    int te = hts[bp*2 + 1];
    const float* ha = ent_att + (size_t)(b*E_ + he)*A_*L_;
    const float* ta = ent_att + (size_t)(b*E_ + te)*A_*L_;
    __shared__ float red[256];
    float lsum = 0.f;
    for (int l = threadIdx.x; l < L_; l += 256) {
        float q = 0.f;
        #pragma unroll
        for (int a = 0; a < A_; ++a) q += ha[a*L_ + l] * ta[a*L_ + l];
        q *= (1.f / A_);
        ht_att[(size_t)bp*L_ + l] = q;
        lsum += q;
    }
    red[threadIdx.x] = lsum;
    __syncthreads();
    for (int s = 128; s > 0; s >>= 1) {
        if (threadIdx.x < s) red[threadIdx.x] += red[threadIdx.x + s];
        __syncthreads();
    }
    float scale = 1.f / (red[0] + 1e-30f);
    for (int l = threadIdx.x; l < L_; l += 256)
        ht_att[(size_t)bp*L_ + l] *= scale;
}

// ---------------- fast transpose body: [K][N] f32 -> [Npad][K] f16 ----------------
// Tile 256k x 64col (4 sub-tiles of 64x64). Phase-1: coalesced reads, conflict-free
// LDS. Phase-2: each thread packs 16 k-contiguous f16, 2x16B stores ->
// 512B-contiguous output per column per block.
static __device__ __forceinline__ void wt_fast_body(const float* __restrict__ in,
                                                    unsigned short* __restrict__ out,
                                                    int K, int N, int kt, int ct, bool guard)
{
    __shared__ float tl[64][65];
    int tid = threadIdx.x;
    int tx = tid & 63, ty = tid >> 6;
    int k0 = kt*256, c0 = ct*64;
    int col = tid >> 2, kq = tid & 3;
    bool cok = !guard || (c0 + tx < N);
    for (int s = 0; s < 4; ++s) {
        int kb = k0 + s*64;
        #pragma unroll
        for (int q = 0; q < 16; ++q) {
            int r = ty*16 + q;
            tl[r][tx] = cok ? in[(size_t)(kb + r)*N + c0 + tx] : 0.f;
        }
        __syncthreads();
        unsigned short pk[16];
        #pragma unroll
        for (int j = 0; j < 16; ++j) pk[j] = f2h(tl[kq*16 + j][col]);
        unsigned short* po = out + (size_t)(c0+col)*K + kb + kq*16;
        *(f16x8*)&po[0] = *(f16x8*)&pk[0];
        *(f16x8*)&po[8] = *(f16x8*)&pk[8];
        __syncthreads();
    }
}

// mega-transpose: W2(2304) | seq(96) | Wh(72) | Wt(72) | Wb(384) = 2928 blocks
__global__ void k_wt_multi(const float* __restrict__ W2, unsigned short* __restrict__ w2t,
                           const float* __restrict__ seq, unsigned short* __restrict__ seqT,
                           const float* __restrict__ Wh, unsigned short* __restrict__ whT,
                           const float* __restrict__ Wt, unsigned short* __restrict__ wtT,
                           const float* __restrict__ Wb, unsigned short* __restrict__ wbt)
{
    int t = blockIdx.x;
    if (t < 2304) {
        wt_fast_body(W2, w2t, KTOT_, 768, t % 192, t / 192, false);
    } else if (t < 2400) {
        t -= 2304; int b = t / 48; t %= 48;
        wt_fast_body(seq + (size_t)b*L_*H_, seqT + (size_t)b*768*L_, L_, 768, t % 4, t / 4, false);
    } else if (t < 2472) {
        t -= 2400;
        wt_fast_body(Wh, whT, 1536, 768, t % 6, t / 6, false);
    } else if (t < 2544) {
        t -= 2472;
        wt_fast_body(Wt, wtT, 1536, 768, t % 6, t / 6, false);
    } else {
        t -= 2544;
        wt_fast_body(Wb, wbt, KTOT_, NL_, t % 192, t / 192, true);
    }
}

// layer-2 weights: K=2304, N=768, grid (9, 12, 2)
__global__ void k_wt2_fast(const float* __restrict__ in0, unsigned short* __restrict__ out0,
                           const float* __restrict__ in1, unsigned short* __restrict__ out1)
{
    const float* in = blockIdx.z ? in1 : in0;
    unsigned short* out = blockIdx.z ? out1 : out0;
    wt_fast_body(in, out, 2304, 768, blockIdx.x, blockIdx.y, false);
}

// ---------------- rs = ht_att @ seq : f16 MFMA, split-K x8 ----------------
__launch_bounds__(256, 3)
__global__ void k_rs_mfma(const float* __restrict__ ht_att, const unsigned short* __restrict__ seqT,
                          float* __restrict__ Cpart)
{
    __shared__ _Float16 Ash[128][64];
    __shared__ _Float16 Bsh[128][64];
    int tid = threadIdx.x;
    int lane = tid & 63, wid = tid >> 6;
    int wr = (wid >> 1)*64, wc = (wid & 1)*64;
    int r16 = lane & 15, g = lane >> 4;
    int z = blockIdx.z;                  // b*8 + kc
    int b = z >> 3, kc = z & 7;
    int c0 = blockIdx.x*128;
    int row0 = blockIdx.y*128;
    const float* At = ht_att + (size_t)b*P_*L_;
    const unsigned short* Bt = seqT + (size_t)b*768*L_;
    int srccol = (lane >> 3);
    int srcch  = (lane & 7) ^ (srccol & 7);

    f32x4 acc[4][4];
    #pragma unroll
    for (int a = 0; a < 4; ++a)
        #pragma unroll
        for (int bq = 0; bq < 4; ++bq) acc[a][bq] = (f32x4){0.f,0.f,0.f,0.f};

    for (int s = 0; s < 2; ++s) {
        __syncthreads();
        #pragma unroll
        for (int q = 0; q < 4; ++q) {
            int idx = q*256 + tid;
            int row = idx >> 3, ch = idx & 7;
            int p = row0 + row; if (p >= P_) p = P_ - 1;
            const float* pp = &At[(size_t)p*L_ + kc*128 + s*64 + ch*8];
            f32x4 a0 = *(const f32x4*)pp;
            f32x4 a1 = *(const f32x4*)(pp + 4);
            f16x8 h;
            h[0]=(_Float16)a0[0]; h[1]=(_Float16)a0[1]; h[2]=(_Float16)a0[2]; h[3]=(_Float16)a0[3];
            h[4]=(_Float16)a1[0]; h[5]=(_Float16)a1[1]; h[6]=(_Float16)a1[2]; h[7]=(_Float16)a1[3];
            *(f16x8*)&Ash[row][(ch ^ (row & 7))*8] = h;
        }
        #pragma unroll
        for (int q = 0; q < 4; ++q) {
            int colb = (q*4 + wid)*8;
            int col = colb + srccol;
            gload_lds16(&Bt[(size_t)(c0+col)*L_ + kc*128 + s*64 + srcch*8],
                        (unsigned short*)&Bsh[colb][0]);
        }
        __syncthreads();
        #pragma unroll
        for (int kk = 0; kk < 2; ++kk) {
            f16x8 bfr[4];
            #pragma unroll
            for (int ni = 0; ni < 4; ++ni)
                bfr[ni] = *(f16x8*)&Bsh[wc + ni*16 + r16][((kk*4 + g) ^ (r16 & 7))*8];
            #pragma unroll
            for (int mi = 0; mi < 4; ++mi) {
                f16x8 afr = *(f16x8*)&Ash[wr + mi*16 + r16][((kk*4 + g) ^ (r16 & 7))*8];
                #pragma unroll
                for (int ni = 0; ni < 4; ++ni)
                    acc[mi][ni] = __builtin_amdgcn_mfma_f32_16x16x32_f16(afr, bfr[ni], acc[mi][ni], 0, 0, 0);
            }
        }
    }

    #pragma unroll
    for (int mi = 0; mi < 4; ++mi)
      #pragma unroll
      for (int ni = 0; ni < 4; ++ni)
        #pragma unroll
        for (int r = 0; r < 4; ++r) {
            int p = row0 + wr + mi*16 + g*4 + r;
            if (p < P_)
                Cpart[((size_t)kc*NP_ + b*P_ + p)*768 + c0 + wc + ni*16 + r16] = acc[mi][ni][r];
        }
}

__global__ void k_rs_reduce(const float* __restrict__ rspart, float* __restrict__ rs)
{
    int idx = blockIdx.x*256 + threadIdx.x;
    if (idx >= NP_*768/4) return;
    f32x4 s = {0.f,0.f,0.f,0.f};
    #pragma unroll
    for (int z = 0; z < NC_; ++z) s += *(const f32x4*)&rspart[(size_t)z*NP_*768 + (size_t)idx*4];
    *(f32x4*)&rs[(size_t)idx*4] = s;
}

// ---------------- legacy rs + gather (fallback path only) ----------------
__global__ void k_rs(const float* __restrict__ seq, const float* __restrict__ ht_att,
                     float* __restrict__ rs)
{
    int blk = blockIdx.x;
    int b = blk / (P_/TP_);
    int p0 = (blk % (P_/TP_)) * TP_;
    const float* sq = seq + (size_t)b*L_*H_;
    float acc[TP_][3];
    #pragma unroll
    for (int t = 0; t < TP_; ++t)
        #pragma unroll
        for (int c = 0; c < 3; ++c) acc[t][c] = 0.f;
    for (int l = 0; l < L_; ++l) {
        float w[TP_];
        #pragma unroll
        for (int t = 0; t < TP_; ++t) w[t] = ht_att[(size_t)(b*P_ + p0 + t)*L_ + l];
        #pragma unroll
        for (int c = 0; c < 3; ++c) {
            float v = sq[(size_t)l*H_ + threadIdx.x + 256*c];
            #pragma unroll
            for (int t = 0; t < TP_; ++t) acc[t][c] += w[t]*v;
        }
    }
    #pragma unroll
    for (int t = 0; t < TP_; ++t)
        #pragma unroll
        for (int c = 0; c < 3; ++c)
            rs[(size_t)(b*P_ + p0 + t)*H_ + threadIdx.x + 256*c] = acc[t][c];
}

__global__ void k_gather(const float* __restrict__ ent_emb, const int* __restrict__ hts,
                         float* __restrict__ hs, float* __restrict__ ts)
{
    int bp = blockIdx.x;
    int b = bp / P_;
    int he = hts[bp*2 + 0];
    int te = hts[bp*2 + 1];
    int h = threadIdx.x;
    hs[(size_t)bp*H_ + h] = ent_emb[(b*E_ + he)*H_ + h];
    ts[(size_t)bp*H_ + h] = ent_emb[(b*E_ + te)*H_ + h];
}

// ---------------- dual reduce + tanh ----------------
__global__ void k_gemm_reduce_tanh2(const float* __restrict__ gpA, const float* __restrict__ gpB,
                                    const float* __restrict__ biasA, const float* __restrict__ biasB,
                                    float* __restrict__ CA, float* __restrict__ CB, int nz)
{
    const float* Cpart = blockIdx.y ? gpB : gpA;
    const float* bias  = blockIdx.y ? biasB : biasA;
    float* C           = blockIdx.y ? CB : CA;
    int idx = blockIdx.x*256 + threadIdx.x;
    if (idx >= NP_*768/4) return;
    int c4 = (idx*4) % 768;
    f32x4 s = *(const f32x4*)&bias[c4];
    for (int z = 0; z < nz; ++z) s += *(const f32x4*)&Cpart[(size_t)z*NP_*768 + (size_t)idx*4];
    f32x4 r;
    #pragma unroll
    for (int j = 0; j < 4; ++j) r[j] = tanhf(s[j]);
    *(f32x4*)&C[(size_t)idx*4] = r;
}

// ---------------- legacy concat GEMM (fallback path only) ----------------
template<int NPARTS, bool DOTANH>
__global__ void k_gemm_concat(const float* __restrict__ A0, const float* __restrict__ A1,
                              const float* __restrict__ A2, const float* __restrict__ W,
                              const float* __restrict__ bias, float* __restrict__ C,
                              int Mrows)
{
    const int BK = 16;
    __shared__ float As[BK][64];
    __shared__ float Bs[BK][64];
    int tid = threadIdx.x;
    int ty = tid >> 4, tx = tid & 15;
    int by = blockIdx.y, bx = blockIdx.x;
    float acc[4][4] = {};
    const int K = NPARTS * 768;
    for (int kk0 = 0; kk0 < K; kk0 += BK) {
        const float* Ap = (kk0 < 768) ? A0 : ((NPARTS >= 3 && kk0 >= 1536) ? A2 : A1);
        int klocal = kk0 % 768;
        {
            int idx = tid * 4;
            int r = idx >> 4;
            int k = idx & 15;
            int row = by*64 + r;
            float4 v = make_float4(0.f,0.f,0.f,0.f);
            if (row < Mrows) v = *(const float4*)(Ap + (size_t)row*768 + klocal + k);
            As[k+0][r] = v.x; As[k+1][r] = v.y; As[k+2][r] = v.z; As[k+3][r] = v.w;
        }
        {
            int idx = tid * 4;
            int k = idx >> 6;
            int c = idx & 63;
            *(float4*)&Bs[k][c] = *(const float4*)(W + (size_t)(kk0 + k)*768 + bx*64 + c);
        }
        __syncthreads();
        #pragma unroll
        for (int k = 0; k < BK; ++k) {
            float a4[4], b4[4];
            *(float4*)a4 = *(float4*)&As[k][ty*4];
            *(float4*)b4 = *(float4*)&Bs[k][tx*4];
            #pragma unroll
            for (int i = 0; i < 4; ++i)
                #pragma unroll
                for (int j = 0; j < 4; ++j) acc[i][j] += a4[i]*b4[j];
        }
        __syncthreads();
    }
    #pragma unroll
    for (int i = 0; i < 4; ++i) {
        int row = by*64 + ty*4 + i;
        if (row >= Mrows) continue;
        #pragma unroll
        for (int j = 0; j < 4; ++j) {
            int col = bx*64 + tx*4 + j;
            float v = acc[i][j] + bias[col];
            if (DOTANH) v = tanhf(v);
            C[(size_t)row*768 + col] = v;
        }
    }
}

// ---------------- dual f16 MFMA concat GEMM (two GEMMs in one launch) ----------------
template<int NSTEP, bool GATHER0>
__launch_bounds__(256, 3)
__global__ void k_gemm_mfma2(const float* __restrict__ A0a, const float* __restrict__ A0b,
                             const float* __restrict__ A1, const float* __restrict__ A2,
                             const int* __restrict__ hts,
                             const unsigned short* __restrict__ WTa, const unsigned short* __restrict__ WTb,
                             float* __restrict__ Cpa, float* __restrict__ Cpb,
                             int Mrows, int Ktot, int partdiv, int nzhalf)
{
    __shared__ _Float16 Ash[128][64];
    __shared__ _Float16 Bsh[128][64];
    int tid = threadIdx.x;
    int lane = tid & 63, wid = tid >> 6;
    int wr = (wid >> 1)*64, wc = (wid & 1)*64;
    int r16 = lane & 15, g = lane >> 4;
    int zz = blockIdx.z;
    int half = zz / nzhalf;
    int z = zz % nzhalf;
    const unsigned short* WT = half ? WTb : WTa;
    float* Cpart = half ? Cpb : Cpa;
    int part = z / partdiv, chunk = z % partdiv;
    int ka = chunk * (NSTEP*64);
    int kb = part*768 + ka;
    const float* A = (part == 0) ? (half ? A0b : A0a) : ((part == 1) ? A1 : A2);
    int c0 = blockIdx.x*128;
    int row0 = blockIdx.y*128;
    int srccol = (lane >> 3);
    int srcch  = (lane & 7) ^ (srccol & 7);

    f32x4 acc[4][4];
    #pragma unroll
    for (int a = 0; a < 4; ++a)
        #pragma unroll
        for (int b = 0; b < 4; ++b) acc[a][b] = (f32x4){0.f,0.f,0.f,0.f};

    for (int s = 0; s < NSTEP; ++s) {
        __syncthreads();
        #pragma unroll
        for (int q = 0; q < 4; ++q) {
            int idx = q*256 + tid;
            int row = idx >> 3, ch = idx & 7;
            int grow = row0 + row; if (grow >= Mrows) grow = Mrows - 1;
            const float* p;
            if (GATHER0 && part == 0) {
                int bb_ = grow / P_;
                int e = hts[grow*2 + half];
                p = &A0a[((size_t)(bb_*E_ + e))*768 + ka + s*64 + ch*8];
            } else {
                p = &A[(size_t)grow*768 + ka + s*64 + ch*8];
            }
            f32x4 a0 = *(const f32x4*)p;
            f32x4 a1 = *(const f32x4*)(p + 4);
            f16x8 h;
            h[0]=(_Float16)a0[0]; h[1]=(_Float16)a0[1]; h[2]=(_Float16)a0[2]; h[3]=(_Float16)a0[3];
            h[4]=(_Float16)a1[0]; h[5]=(_Float16)a1[1]; h[6]=(_Float16)a1[2]; h[7]=(_Float16)a1[3];
            *(f16x8*)&Ash[row][(ch ^ (row & 7))*8] = h;
        }
        #pragma unroll
        for (int q = 0; q < 4; ++q) {
            int colb = (q*4 + wid)*8;
            int col = colb + srccol;
            gload_lds16(&WT[(size_t)(c0+col)*Ktot + kb + s*64 + srcch*8],
                        (unsigned short*)&Bsh[colb][0]);
        }
        __syncthreads();
        #pragma unroll
        for (int kk = 0; kk < 2; ++kk) {
            f16x8 bfr[4];
            #pragma unroll
            for (int ni = 0; ni < 4; ++ni)
                bfr[ni] = *(f16x8*)&Bsh[wc + ni*16 + r16][((kk*4 + g) ^ (r16 & 7))*8];
            #pragma unroll
            for (int mi = 0; mi < 4; ++mi) {
                f16x8 afr = *(f16x8*)&Ash[wr + mi*16 + r16][((kk*4 + g) ^ (r16 & 7))*8];
                #pragma unroll
                for (int ni = 0; ni < 4; ++ni)
                    acc[mi][ni] = __builtin_amdgcn_mfma_f32_16x16x32_f16(afr, bfr[ni], acc[mi][ni], 0, 0, 0);
            }
        }
    }

    #pragma unroll
    for (int mi = 0; mi < 4; ++mi)
      #pragma unroll
      for (int ni = 0; ni < 4; ++ni)
        #pragma unroll
        for (int r = 0; r < 4; ++r) {
            int row = row0 + wr + mi*16 + g*4 + r;
            if (row < Mrows)
                Cpart[((size_t)z*Mrows + row)*768 + c0 + wc + ni*16 + r16] = acc[mi][ni][r];
        }
}

// ---------------- f16 MFMA block-bilinear GEMM (R9 proven structure) ----------------
template<int ILEN, bool SWZ>
__launch_bounds__(256, 3)
__global__ void k_bb_mfma(const float* __restrict__ U, const float* __restrict__ V,
                          const unsigned short* __restrict__ BT, float* __restrict__ Cpart,
                          int Mrows, int ldc)
{
    const int ISPLIT = 64 / ILEN;
    __shared__ unsigned short Ush[128][ILEN + 2];
    __shared__ _Float16 Bs[2][128][64];
    int tid = threadIdx.x;
    int lane = tid & 63, wid = tid >> 6;
    int wr = (wid >> 1)*64, wc = (wid & 1)*64;
    int r16 = lane & 15, g = lane >> 4;
    int bx = blockIdx.x, by = blockIdx.y, z = blockIdx.z;
    if (SWZ) {
        int h = bx + 6*by + 54*z;
        int x = h & 7, j = h >> 3;
        int p = x*9 + j/9;
        by = j % 9;
        bx = p % 6;
        z  = p / 6;
    }
    int kz = z / ISPLIT, si = z % ISPLIT;
    int ibeg = si * ILEN;
    int c0 = bx*128;
    int row0 = by*128;
    int srccol = (lane >> 3);
    int srcch  = (lane & 7) ^ (srccol & 7);
    const unsigned short* BTkz = BT + (size_t)kz*4096;

    #pragma unroll
    for (int q = 0; q < (128*ILEN)/1024; ++q) {
        int idx = (q*256 + tid)*4;
        int r = idx / ILEN, c = idx % ILEN;
        int row = row0 + r; if (row >= Mrows) row = Mrows - 1;
        f32x4 v = *(const f32x4*)&U[(size_t)row*EMB_ + kz*64 + ibeg + c];
        Ush[r][c+0] = f2h(v[0]); Ush[r][c+1] = f2h(v[1]);
        Ush[r][c+2] = f2h(v[2]); Ush[r][c+3] = f2h(v[3]);
    }
    f16x8 vfh[2][4];
    #pragma unroll
    for (int kk = 0; kk < 2; ++kk)
      #pragma unroll
      for (int mi = 0; mi < 4; ++mi) {
        int row = row0 + wr + mi*16 + r16; if (row >= Mrows) row = Mrows - 1;
        const float* p = &V[(size_t)row*EMB_ + kz*64 + kk*32 + g*8];
        f16x8 t;
        #pragma unroll
        for (int e = 0; e < 8; ++e) t[e] = (_Float16)p[e];
        vfh[kk][mi] = t;
      }
    // stage panel i=ibeg into Bs[0] via async global->LDS
    #pragma unroll
    for (int q = 0; q < 4; ++q) {
        int colb = (q*4 + wid)*8;
        int col = colb + srccol;
        gload_lds16(&BTkz[(size_t)(c0+col)*KTOT_ + (size_t)ibeg*64 + srcch*8],
                    (unsigned short*)&Bs[0][colb][0]);
    }
    __syncthreads();

    f32x4 acc[4][4];
    #pragma unroll
    for (int a = 0; a < 4; ++a)
        #pragma unroll
        for (int b = 0; b < 4; ++b) acc[a][b] = (f32x4){0.f,0.f,0.f,0.f};

    for (int ii = 0; ii < ILEN; ++ii) {
        int cur = ii & 1, nxt = cur ^ 1;
        if (ii < ILEN-1) {
            #pragma unroll
            for (int q = 0; q < 4; ++q) {
                int colb = (q*4 + wid)*8;
                int col = colb + srccol;
                gload_lds16(&BTkz[(size_t)(c0+col)*KTOT_ + (size_t)(ibeg+ii+1)*64 + srcch*8],
                            (unsigned short*)&Bs[nxt][colb][0]);
            }
        }
        f16x8 u8[4];
        #pragma unroll
        for (int mi = 0; mi < 4; ++mi) {
            unsigned short ub = Ush[wr + mi*16 + r16][ii];
            _Float16 uh; __builtin_memcpy(&uh, &ub, 2);
            #pragma unroll
            for (int e = 0; e < 8; ++e) u8[mi][e] = uh;
        }
        #pragma unroll
        for (int kk = 0; kk < 2; ++kk) {
            f16x8 bfr[4];
            #pragma unroll
            for (int ni = 0; ni < 4; ++ni) {
                int row = wc + ni*16 + r16;
                bfr[ni] = *(f16x8*)&Bs[cur][row][((kk*4 + g) ^ (r16 & 7))*8];
            }
            #pragma unroll
            for (int mi = 0; mi < 4; ++mi) {
                f16x8 afr = u8[mi] * vfh[kk][mi];
                #pragma unroll
                for (int ni = 0; ni < 4; ++ni)
                    acc[mi][ni] = __builtin_amdgcn_mfma_f32_16x16x32_f16(afr, bfr[ni], acc[mi][ni], 0, 0, 0);
            }
        }
        __syncthreads();
    }

    #pragma unroll
    for (int mi = 0; mi < 4; ++mi)
      #pragma unroll
      for (int ni = 0; ni < 4; ++ni)
        #pragma unroll
        for (int r = 0; r < 4; ++r) {
            int row = row0 + wr + mi*16 + g*4 + r;
            if (row < Mrows)
                Cpart[((size_t)z*Mrows + row)*ldc + c0 + wc + ni*16 + r16] = acc[mi][ni][r];
        }
}

// ---------------- reduce split-K partials (+bias) ----------------
__global__ void k_reduce_feat(const float* __restrict__ part, const float* __restrict__ bias,
                              float* __restrict__ out)
{
    int idx = blockIdx.x*256 + threadIdx.x;
    if (idx >= (NP_*768)/4) return;
    int c4 = (idx*4) % 768;
    f32x4 s = *(const f32x4*)&bias[c4];
    #pragma unroll
    for (int z = 0; z < NBLK_; ++z) s += *(const f32x4*)&part[(size_t)z*NP_*768 + (size_t)idx*4];
    *(f32x4*)&out[(size_t)idx*4] = s;
}

__global__ void k_reduce_logits(const float* __restrict__ part, const float* __restrict__ bb,
                                float* __restrict__ out, int nz)
{
    int idx = blockIdx.x*256 + threadIdx.x;
    if (idx >= NP_*NL_) return;
    int n = idx / NL_, c = idx % NL_;
    float s = bb[c];
    for (int z = 0; z < nz; ++z) s += part[(size_t)z*NP_*128 + (size_t)n*128 + c];
    out[idx] = s;
}

// ---------------- fallback fp32 bilinear GEMM ----------------
template<bool GUARD, bool SPLITK>
__global__ void k_bbgemm(const float* __restrict__ U, const float* __restrict__ V,
                         const float* __restrict__ W, const float* __restrict__ bias,
                         float* __restrict__ C, int Mrows, int Ncols, int ldw, int ldc)
{
    __shared__ float Us[64][68];
    __shared__ float Vs[64][68];
    __shared__ float Bsh[16][64];
    int tid = threadIdx.x;
    int ty = tid >> 4, tx = tid & 15;
    int by = blockIdx.y, bx = blockIdx.x;
    int c0 = bx*64;
    float acc[4][4] = {};
    int kbeg = SPLITK ? blockIdx.z : 0;
    int kend = SPLITK ? blockIdx.z + 1 : NBLK_;
    for (int k = kbeg; k < kend; ++k) {
        #pragma unroll
        for (int e = 0; e < 4; ++e) {
            int idx = (e*256 + tid)*4;
            int r = idx >> 6, c = idx & 63;
            int row = by*64 + r;
            float4 u = make_float4(0.f,0.f,0.f,0.f), vv = make_float4(0.f,0.f,0.f,0.f);
            if (row < Mrows) {
                u  = *(const float4*)(U + (size_t)row*EMB_ + k*BLK_ + c);
                vv = *(const float4*)(V + (size_t)row*EMB_ + k*BLK_ + c);
            }
            *(float4*)&Us[r][c] = u;
            *(float4*)&Vs[r][c] = vv;
        }
        __syncthreads();
        for (int t = 0; t < 256; ++t) {
            int i = t >> 2;
            int jb = (t & 3) * 16;
            {
                int idx = tid * 4;
                int kk = idx >> 6, c = idx & 63;
                size_t wrow = (size_t)(k*256 + t)*16 + kk;
                if (GUARD) {
                    #pragma unroll
                    for (int q = 0; q < 4; ++q) {
                        int col = c0 + c + q;
                        Bsh[kk][c+q] = (col < Ncols) ? W[wrow*ldw + col] : 0.f;
                    }
                } else {
                    *(float4*)&Bsh[kk][c] = *(const float4*)(W + wrow*ldw + c0 + c);
                }
            }
            __syncthreads();
            float u[4];
            #pragma unroll
            for (int r = 0; r < 4; ++r) u[r] = Us[ty*4+r][i];
            #pragma unroll
            for (int kk = 0; kk < 16; ++kk) {
                float b4[4];
                *(float4*)b4 = *(float4*)&Bsh[kk][tx*4];
                #pragma unroll
                for (int r = 0; r < 4; ++r) {
                    float a = u[r] * Vs[ty*4+r][jb+kk];
                    #pragma unroll
                    for (int j = 0; j < 4; ++j) acc[r][j] += a*b4[j];
                }
            }
            __syncthreads();
        }
    }
    #pragma unroll
    for (int r = 0; r < 4; ++r) {
        int row = by*64 + ty*4 + r;
        if (row >= Mrows) continue;
        #pragma unroll
        for (int j = 0; j < 4; ++j) {
            int col = c0 + tx*4 + j;
            if (GUARD && col >= Ncols) continue;
            float v = acc[r][j];
            if (!SPLITK) v += bias[col];
            size_t out_idx = SPLITK ? ((size_t)(blockIdx.z*Mrows + row)*ldc + col)
                                    : ((size_t)row*ldc + col);
            C[out_idx] = v;
        }
    }
}

__global__ void k_logits_reduce_old(const float* __restrict__ part, const float* __restrict__ bb,
                                    float* __restrict__ out)
{
    int idx = blockIdx.x*256 + threadIdx.x;
    if (idx >= NP_*NL_) return;
    int col = idx % NL_;
    float s = bb[col];
    #pragma unroll
    for (int z = 0; z < NBLK_; ++z) s += part[(size_t)z*NP_*NL_ + idx];
    out[idx] = s;
}

extern "C" void kernel_launch(void* const* d_in, const int* in_sizes, int n_in,
                              void* d_out, int out_size, void* d_ws, size_t ws_size,
                              hipStream_t stream)
{
    (void)in_sizes; (void)n_in; (void)out_size;
    const float* seq  = (const float*)d_in[0];
    const float* att  = (const float*)d_in[1];
    const float* mask = (const float*)d_in[2];
    const float* Wh   = (const float*)d_in[3];
    const float* bh   = (const float*)d_in[4];
    const float* Wt   = (const float*)d_in[5];
    const float* bt   = (const float*)d_in[6];
    const float* Wh2  = (const float*)d_in[7];
    const float* bh2  = (const float*)d_in[8];
    const float* Wt2  = (const float*)d_in[9];
    const float* bt2  = (const float*)d_in[10];
    const float* W2   = (const float*)d_in[11];
    const float* b2   = (const float*)d_in[12];
    const float* Wb   = (const float*)d_in[13];
    const float* bb   = (const float*)d_in[14];
    const int* midx   = (const int*)d_in[15];
    const int* hts    = (const int*)d_in[16];
    float* out = (float*)d_out;
    float* ws  = (float*)d_ws;

    float* ent_emb = ws;                        // 36864
    float* ent_att = ent_emb + 36864;           // 589824 (mfma: whT after ht_att)
    float* ht_att  = ent_att + 589824;          // 1130496 (mfma: wh2T after rs)
    float* rs      = ht_att + 1130496;          // 847872 each below
    float* hs      = rs   + 847872;             // mfma path: seqT (f16)
    float* ts      = hs   + 847872;             // mfma path: wtT (f16)
    float* hs1     = ts   + 847872;
    float* ts1     = hs1  + 847872;
    float* feat    = ts1  + 847872;
    float* hs2     = feat + 847872;
    float* ts2     = hs2  + 847872;
    float* featpart = ts2 + 847872;             // 10174464 floats (multi-use scratch)
    float* spare    = featpart + 10174464;      // 1695744 floats (mfma: wt2T)
    unsigned short* w2t = (unsigned short*)(spare + 1695744);             // 37748736 shorts
    unsigned short* Rrgn = (unsigned short*)(spare + 1695744 + 18874368); // 6291456 shorts
    const size_t need_bytes = (size_t)42430464 * 4;      // ~169.7 MB
    const bool use_mfma = (ws_size >= need_bytes);

    // mfma-path aliases (sequential lifetimes):
    unsigned short* whT  = (unsigned short*)ent_att;  // 1179648 sh (exact fit)
    unsigned short* wtT  = (unsigned short*)ts;       // 1179648 sh <= 1695744
    unsigned short* wh2T = (unsigned short*)ht_att;   // 1769472 sh <= 2260992 (after rs done)
    unsigned short* wt2T = (unsigned short*)spare;    // 1769472 sh <= 3391488
    unsigned short* wbt  = Rrgn;                      // 6291456 sh (exact fit, persistent)
    unsigned short* seqT = (unsigned short*)hs;

    float* rspart  = featpart;                  // 8*1104*768
    float* gpA     = featpart;                  // 6 planes = 5087232
    float* gpB     = featpart + 5087232;
    float* logpart = featpart;                  // 48*1104*128

    k_ent_emb<<<dim3(B_*E_), dim3(H_), 0, stream>>>(seq, mask, midx, ent_emb);
    k_ent_att<<<dim3(B_*E_*A_), dim3(256), 0, stream>>>(att, mask, midx, ent_att);
    k_ht_att<<<dim3(NP_), dim3(256), 0, stream>>>(ent_att, hts, ht_att);

    if (use_mfma) {
        // all transposes whose outputs are ready (ent_att dead after ht_att)
        k_wt_multi<<<dim3(2928), dim3(256), 0, stream>>>(W2, w2t, seq, seqT,
                                                         Wh, whT, Wt, wtT, Wb, wbt);

        k_rs_mfma<<<dim3(6, 5, 16), dim3(256), 0, stream>>>(ht_att, seqT, rspart);
        k_rs_reduce<<<dim3(828), dim3(256), 0, stream>>>(rspart, rs);

        k_gemm_mfma2<4, true><<<dim3(6, 9, 12), dim3(256), 0, stream>>>(
            ent_emb, ent_emb, rs, rs, hts, whT, wtT, gpA, gpB, NP_, 1536, 3, 6);
        k_gemm_reduce_tanh2<<<dim3(828, 2), dim3(256), 0, stream>>>(gpA, gpB, bh, bt, hs1, ts1, 6);

        k_bb_mfma<64, true><<<dim3(6, 9, NBLK_), dim3(256), 0, stream>>>(hs1, ts1, w2t, featpart, NP_, 768);
        k_reduce_feat<<<dim3((NP_*768/4 + 255)/256), dim3(256), 0, stream>>>(featpart, b2, feat);

        // layer-2 weight transposes (ht_att dead after rs_mfma)
        k_wt2_fast<<<dim3(9, 12, 2), dim3(256), 0, stream>>>(Wh2, wh2T, Wt2, wt2T);

        k_gemm_mfma2<6, false><<<dim3(6, 9, 12), dim3(256), 0, stream>>>(
            hs1, ts1, rs, feat, hts, wh2T, wt2T, gpA, gpB, NP_, 2304, 2, 6);
        k_gemm_reduce_tanh2<<<dim3(828, 2), dim3(256), 0, stream>>>(gpA, gpB, bh2, bt2, hs2, ts2, 6);

        k_bb_mfma<16, false><<<dim3(1, 9, NBLK_*4), dim3(256), 0, stream>>>(hs2, ts2, wbt, logpart, NP_, 128);
        k_reduce_logits<<<dim3((NP_*NL_ + 255)/256), dim3(256), 0, stream>>>(logpart, bb, out, NBLK_*4);
    } else {
        k_rs<<<dim3(B_*(P_/TP_)), dim3(256), 0, stream>>>(seq, ht_att, rs);
        k_gather<<<dim3(NP_), dim3(H_), 0, stream>>>(ent_emb, hts, hs, ts);
        dim3 gg(12, (NP_+63)/64);
        k_gemm_concat<2, true><<<gg, dim3(256), 0, stream>>>(hs, rs, nullptr, Wh, bh, hs1, NP_);
        k_gemm_concat<2, true><<<gg, dim3(256), 0, stream>>>(ts, rs, nullptr, Wt, bt, ts1, NP_);
        float* lpart = featpart;
        k_bbgemm<false, false><<<gg, dim3(256), 0, stream>>>(hs1, ts1, W2, b2, feat, NP_, 768, 768, 768);
        k_gemm_concat<3, true><<<gg, dim3(256), 0, stream>>>(hs1, rs, feat, Wh2, bh2, hs2, NP_);
        k_gemm_concat<3, true><<<gg, dim3(256), 0, stream>>>(ts1, rs, feat, Wt2, bt2, ts2, NP_);
        k_bbgemm<true, true><<<dim3(2, (NP_+63)/64, NBLK_), dim3(256), 0, stream>>>(
            hs2, ts2, Wb, nullptr, lpart, NP_, NL_, NL_, NL_);
        k_logits_reduce_old<<<dim3((NP_*NL_ + 255)/256), dim3(256), 0, stream>>>(lpart, bb, out);
    }
}